// Round 3
// baseline (286.324 us; speedup 1.0000x reference)
//
#include <hip/hip_runtime.h>

// Problem constants
#define BB      16384
#define IN_DIM  256
#define NE      32
#define H1D     64
#define H2D     256
#define H3D     128
#define NOUT    128

typedef __bf16 bf16_t;
typedef __bf16 bf16x4_t __attribute__((ext_vector_type(4)));
typedef __bf16 bf16x8  __attribute__((ext_vector_type(8)));
typedef float  f32x4   __attribute__((ext_vector_type(4)));

// ---- workspace: fragment-ordered bf16 weights ----
// Per expert, 160 "sets" of 64 lanes x 16B, contiguous in set order:
//   sets [0,32):   L1  (tile 0..3, ks 0..7)   K=256, N=64
//   sets [32,64):  L2  (tile 0..15, ks 0..1)  K=64,  N=256
//   sets [64,128): L3  (tile 0..7,  ks 0..7)  K=256, N=128
//   sets [128,144):L4  (tile 0..3,  ks 0..3)  K=128, N=64
//   sets [144,160):L5  (tile 0..7,  ks 0..1)  K=64,  N=128
// frag elem: dst[(set*64+lane)*8 + j] = W[k0+j][tile*16+(lane&15)], k0=ks*32+(lane>>4)*8
#define OFF_WF   ((size_t)0)
#define OFF_WGF  ((size_t)NE * 81920 * 2)     // Wg frags: 16 sets = 16 KB

// ---- prep: one thread per fragment (328,704 threads total) ----
__global__ __launch_bounds__(256) void build_frags(
    const float* __restrict__ W1, const float* __restrict__ W2,
    const float* __restrict__ W3, const float* __restrict__ W4,
    const float* __restrict__ W5, const float* __restrict__ Wg,
    bf16_t* __restrict__ Wf, bf16_t* __restrict__ Wgf)
{
    const int g    = blockIdx.x * 256 + threadIdx.x;
    const int lane = g & 63;
    const int set  = g >> 6;            // 0 .. 5135
    const float* src; bf16_t* dst; int N, t, ks;
    if (set < 5120) {
        const int e = set / 160;
        const int s = set % 160;
        dst = Wf + (size_t)e * 81920 + ((size_t)s * 64 + lane) * 8;
        if (s < 32)       { t = s >> 3;         ks = s & 7;         N = 64;  src = W1 + (size_t)e * 16384; }
        else if (s < 64)  { t = (s - 32) >> 1;  ks = (s - 32) & 1;  N = 256; src = W2 + (size_t)e * 16384; }
        else if (s < 128) { t = (s - 64) >> 3;  ks = (s - 64) & 7;  N = 128; src = W3 + (size_t)e * 32768; }
        else if (s < 144) { t = (s - 128) >> 2; ks = (s - 128) & 3; N = 64;  src = W4 + (size_t)e * 8192;  }
        else              { t = (s - 144) >> 1; ks = (s - 144) & 1; N = 128; src = W5 + (size_t)e * 8192;  }
    } else {
        const int s = set - 5120;
        t = s >> 3; ks = s & 7; N = 32; src = Wg;
        dst = Wgf + ((size_t)s * 64 + lane) * 8;
    }
    const int f  = t * 16 + (lane & 15);
    const int k0 = ks * 32 + (lane >> 4) * 8;
    bf16x8 o;
#pragma unroll
    for (int j = 0; j < 8; j++) o[j] = (bf16_t)src[(size_t)(k0 + j) * N + f];
    *(bf16x8*)dst = o;
}

// ---- swizzled LDS addressing: 16B-granule XOR with row&7 (bank-balanced) ----
template<int RS>
__device__ __forceinline__ void* swzp(char* base, int row, int byteoff) {
    const int g = byteoff >> 4;
    return (void*)(base + ((row << RS) | ((g ^ (row & 7)) << 4) | (byteoff & 15)));
}

// ---- LDS carve: 64-row tile ----
#define L_H1   0          // h1 [64][128B]  RS=7   8 KB
#define L_SX   8192       // x  [64][512B]  RS=9  32 KB
#define L_H2   40960      // h2 [64][512B]  RS=9  32 KB
#define L_H3   73728      // h3 [64][256B]  RS=8  16 KB (alias gating logits [64][36] f32)
#define L_H4   90112      // h4 [64][128B]  RS=7   8 KB
#define L_SG   98304      // g  [32e][64b] f32     8 KB
#define L_TOT  106496

// ---- main: 64-row tile, 8 waves, 256 blocks; x in regs; 2 barriers/expert ----
__global__ __launch_bounds__(512, 2) void moe_main(
    const float* __restrict__ x, const bf16_t* __restrict__ Wf,
    const bf16_t* __restrict__ Wgf, const float* __restrict__ bg,
    const float* __restrict__ b1, const float* __restrict__ b2,
    const float* __restrict__ b3, const float* __restrict__ b4,
    const float* __restrict__ b5, float* __restrict__ out)
{
    __shared__ __align__(16) char lds[L_TOT];
    char* sX = lds + L_SX;
    char* h1 = lds + L_H1;
    char* h2 = lds + L_H2;
    char* h3 = lds + L_H3;
    char* h4 = lds + L_H4;
    float* sG = (float*)(lds + L_SG);

    const int tid  = threadIdx.x;
    const int w    = tid >> 6;
    const int lane = tid & 63;
    const int c    = lane & 15;
    const int q    = lane >> 4;
    const int fg   = w & 3;             // f-tile group for L1/L4
    const int mh   = w >> 2;            // m-half for L1/L4
    const int b0   = blockIdx.x * 64;

    bf16x8 wA[8], wB[2][2], wC[8], wD[4], wE[2];
    bf16x8 xa[2][8];

    // early issue: wA(0) [L1 tile fg], wB(0) [L2 tiles w*2..+1]
#pragma unroll
    for (int ks = 0; ks < 8; ks++)
        wA[ks] = *(const bf16x8*)(Wf + ((size_t)(fg * 8 + ks) * 64 + lane) * 8);
#pragma unroll
    for (int nt = 0; nt < 2; nt++)
#pragma unroll
        for (int ks = 0; ks < 2; ks++)
            wB[nt][ks] = *(const bf16x8*)(Wf + 16384 + ((size_t)((w * 2 + nt) * 2 + ks) * 64 + lane) * 8);

    // ---- stage x: 64x256 fp32 -> bf16, swizzled ----
    {
        const int r  = tid >> 3;
        const int c0 = (tid & 7) * 32;
        const float* sp = x + (size_t)(b0 + r) * IN_DIM + c0;
#pragma unroll
        for (int jj = 0; jj < 4; jj++) {
            const float4 v0 = *(const float4*)(sp + jj * 8);
            const float4 v1 = *(const float4*)(sp + jj * 8 + 4);
            bf16x8 o = { (bf16_t)v0.x, (bf16_t)v0.y, (bf16_t)v0.z, (bf16_t)v0.w,
                         (bf16_t)v1.x, (bf16_t)v1.y, (bf16_t)v1.z, (bf16_t)v1.w };
            *(bf16x8*)swzp<9>(sX, r, c0 * 2 + jj * 16) = o;
        }
    }
    __syncthreads();

    // ---- gating logits -> h3 as [64][36] f32; xa loads from sX ----
    {
        const int t = w & 1, m = w >> 1;
        f32x4 acc = (f32x4){0.f, 0.f, 0.f, 0.f};
#pragma unroll
        for (int ks = 0; ks < 8; ks++) {
            bf16x8 xv = *(const bf16x8*)swzp<9>(sX, m * 16 + c, ks * 64 + q * 16);
            bf16x8 wg = *(const bf16x8*)(Wgf + ((size_t)(t * 8 + ks) * 64 + lane) * 8);
            acc = __builtin_amdgcn_mfma_f32_16x16x32_bf16(wg, xv, acc, 0, 0, 0);
        }
        const float4 bgv = *(const float4*)(bg + t * 16 + q * 4);
        float* sLgF = (float*)h3;
        *(float4*)(sLgF + (size_t)(m * 16 + c) * 36 + t * 16 + q * 4) =
            (float4){acc[0] + bgv.x, acc[1] + bgv.y, acc[2] + bgv.z, acc[3] + bgv.w};
    }
#pragma unroll
    for (int mm = 0; mm < 2; mm++)
#pragma unroll
        for (int ks = 0; ks < 8; ks++)
            xa[mm][ks] = *(const bf16x8*)swzp<9>(sX, (mh * 2 + mm) * 16 + c, ks * 64 + q * 16);
    __syncthreads();

    // ---- softmax -> sG ; L1(0) -> h1 (pure reg MFMA + LDS write) ----
    {
        const int r = tid >> 3;
        const int j = tid & 7;
        const float* sLgF = (const float*)h3;
        float4 l = *(const float4*)(sLgF + (size_t)r * 36 + j * 4);
        float mx = fmaxf(fmaxf(l.x, l.y), fmaxf(l.z, l.w));
#pragma unroll
        for (int off = 1; off < 8; off <<= 1) mx = fmaxf(mx, __shfl_xor(mx, off));
        float e0 = __expf(l.x - mx), e1 = __expf(l.y - mx),
              e2 = __expf(l.z - mx), e3 = __expf(l.w - mx);
        float sm = e0 + e1 + e2 + e3;
#pragma unroll
        for (int off = 1; off < 8; off <<= 1) sm += __shfl_xor(sm, off);
        const float rs = 1.f / sm;
        sG[(j * 4 + 0) * 64 + r] = e0 * rs;
        sG[(j * 4 + 1) * 64 + r] = e1 * rs;
        sG[(j * 4 + 2) * 64 + r] = e2 * rs;
        sG[(j * 4 + 3) * 64 + r] = e3 * rs;
    }
    {
        const float4 bv = *(const float4*)(b1 + fg * 16 + q * 4);
#pragma unroll
        for (int mm = 0; mm < 2; mm++) {
            const int m = mh * 2 + mm;
            f32x4 acc = (f32x4){0.f, 0.f, 0.f, 0.f};
#pragma unroll
            for (int ks = 0; ks < 8; ks++)
                acc = __builtin_amdgcn_mfma_f32_16x16x32_bf16(wA[ks], xa[mm][ks], acc, 0, 0, 0);
            bf16x4_t hv = { (bf16_t)fmaxf(acc[0] + bv.x, 0.f),
                            (bf16_t)fmaxf(acc[1] + bv.y, 0.f),
                            (bf16_t)fmaxf(acc[2] + bv.z, 0.f),
                            (bf16_t)fmaxf(acc[3] + bv.w, 0.f) };
            *(bf16x4_t*)swzp<7>(h1, m * 16 + c, fg * 32 + q * 8) = hv;
        }
    }
    __syncthreads();

    float oacc[4][4];
#pragma unroll
    for (int m = 0; m < 4; m++)
#pragma unroll
        for (int r = 0; r < 4; r++) oacc[m][r] = 0.f;

    auto do_l5 = [&](int ep) {
        const float4 bv = *(const float4*)(b5 + (size_t)ep * NOUT + w * 16 + q * 4);
#pragma unroll
        for (int m = 0; m < 4; m++) {
            f32x4 acc = (f32x4){0.f, 0.f, 0.f, 0.f};
#pragma unroll
            for (int ks = 0; ks < 2; ks++) {
                bf16x8 ha = *(const bf16x8*)swzp<7>(h4, m * 16 + c, ks * 64 + q * 16);
                acc = __builtin_amdgcn_mfma_f32_16x16x32_bf16(wE[ks], ha, acc, 0, 0, 0);
            }
            const float gv = sG[ep * 64 + m * 16 + c];
            oacc[m][0] += gv * (acc[0] + bv.x);
            oacc[m][1] += gv * (acc[1] + bv.y);
            oacc[m][2] += gv * (acc[2] + bv.z);
            oacc[m][3] += gv * (acc[3] + bv.w);
        }
    };

    // ---- expert loop: X = {L2(e), L4(e-1)}, Y = {L3(e), L1(e+1), L5(e-1)} ----
    for (int e = 0; e < NE; e++) {
        const bf16_t* We  = Wf + (size_t)e * 81920;
        const bf16_t* Wen = Wf + (size_t)((e + 1) & 31) * 81920;
        const bf16_t* Wep = Wf + (size_t)((e - 1) & 31) * 81920;

        // ---- X phase: issue wC(e), wA(e+1), wE(e-1) ----
#pragma unroll
        for (int ks = 0; ks < 8; ks++)
            wC[ks] = *(const bf16x8*)(We + 32768 + ((size_t)(w * 8 + ks) * 64 + lane) * 8);
#pragma unroll
        for (int ks = 0; ks < 8; ks++)
            wA[ks] = *(const bf16x8*)(Wen + ((size_t)(fg * 8 + ks) * 64 + lane) * 8);
#pragma unroll
        for (int ks = 0; ks < 2; ks++)
            wE[ks] = *(const bf16x8*)(Wep + 73728 + ((size_t)(w * 2 + ks) * 64 + lane) * 8);

        // L2(e): h1 -> h2 (tiles w*2..+1, all m)
        {
            float4 bv[2];
#pragma unroll
            for (int nt = 0; nt < 2; nt++)
                bv[nt] = *(const float4*)(b2 + (size_t)e * H2D + (w * 2 + nt) * 16 + q * 4);
#pragma unroll
            for (int m = 0; m < 4; m++) {
                bf16x8 ha[2];
#pragma unroll
                for (int ks = 0; ks < 2; ks++)
                    ha[ks] = *(const bf16x8*)swzp<7>(h1, m * 16 + c, ks * 64 + q * 16);
                f32x4 acc[2];
#pragma unroll
                for (int nt = 0; nt < 2; nt++) acc[nt] = (f32x4){0.f, 0.f, 0.f, 0.f};
#pragma unroll
                for (int nt = 0; nt < 2; nt++)
#pragma unroll
                    for (int ks = 0; ks < 2; ks++)
                        acc[nt] = __builtin_amdgcn_mfma_f32_16x16x32_bf16(wB[nt][ks], ha[ks], acc[nt], 0, 0, 0);
#pragma unroll
                for (int nt = 0; nt < 2; nt++) {
                    bf16x4_t hv = { (bf16_t)fmaxf(acc[nt][0] + bv[nt].x, 0.f),
                                    (bf16_t)fmaxf(acc[nt][1] + bv[nt].y, 0.f),
                                    (bf16_t)fmaxf(acc[nt][2] + bv[nt].z, 0.f),
                                    (bf16_t)fmaxf(acc[nt][3] + bv[nt].w, 0.f) };
                    *(bf16x4_t*)swzp<9>(h2, m * 16 + c, (w * 2 + nt) * 32 + q * 8) = hv;
                }
            }
        }
        // L4(e-1): h3 -> h4 (tile fg, rows mh)
        if (e > 0) {
            const float4 bv = *(const float4*)(b4 + (size_t)(e - 1) * H1D + fg * 16 + q * 4);
#pragma unroll
            for (int mm = 0; mm < 2; mm++) {
                const int m = mh * 2 + mm;
                f32x4 acc = (f32x4){0.f, 0.f, 0.f, 0.f};
#pragma unroll
                for (int ks = 0; ks < 4; ks++) {
                    bf16x8 ha = *(const bf16x8*)swzp<8>(h3, m * 16 + c, ks * 64 + q * 16);
                    acc = __builtin_amdgcn_mfma_f32_16x16x32_bf16(wD[ks], ha, acc, 0, 0, 0);
                }
                bf16x4_t hv = { (bf16_t)fmaxf(acc[0] + bv.x, 0.f),
                                (bf16_t)fmaxf(acc[1] + bv.y, 0.f),
                                (bf16_t)fmaxf(acc[2] + bv.z, 0.f),
                                (bf16_t)fmaxf(acc[3] + bv.w, 0.f) };
                *(bf16x4_t*)swzp<7>(h4, m * 16 + c, fg * 32 + q * 8) = hv;
            }
        }
        __syncthreads();

        // ---- Y phase: issue wB(e+1), wD(e) ----
#pragma unroll
        for (int nt = 0; nt < 2; nt++)
#pragma unroll
            for (int ks = 0; ks < 2; ks++)
                wB[nt][ks] = *(const bf16x8*)(Wen + 16384 + ((size_t)((w * 2 + nt) * 2 + ks) * 64 + lane) * 8);
#pragma unroll
        for (int ks = 0; ks < 4; ks++)
            wD[ks] = *(const bf16x8*)(We + 65536 + ((size_t)(fg * 4 + ks) * 64 + lane) * 8);

        // L3(e): h2 -> h3 (tile w, all m)
        {
            const float4 bv = *(const float4*)(b3 + (size_t)e * H3D + w * 16 + q * 4);
#pragma unroll
            for (int m = 0; m < 4; m++) {
                f32x4 acc = (f32x4){0.f, 0.f, 0.f, 0.f};
#pragma unroll
                for (int ks = 0; ks < 8; ks++) {
                    bf16x8 ha = *(const bf16x8*)swzp<9>(h2, m * 16 + c, ks * 64 + q * 16);
                    acc = __builtin_amdgcn_mfma_f32_16x16x32_bf16(wC[ks], ha, acc, 0, 0, 0);
                }
                bf16x4_t hv = { (bf16_t)fmaxf(acc[0] + bv.x, 0.f),
                                (bf16_t)fmaxf(acc[1] + bv.y, 0.f),
                                (bf16_t)fmaxf(acc[2] + bv.z, 0.f),
                                (bf16_t)fmaxf(acc[3] + bv.w, 0.f) };
                *(bf16x4_t*)swzp<8>(h3, m * 16 + c, w * 32 + q * 8) = hv;
            }
        }
        // L1(e+1): xa(reg) -> h1 (tile fg, rows mh)
        if (e < NE - 1) {
            const float4 bv = *(const float4*)(b1 + (size_t)(e + 1) * H1D + fg * 16 + q * 4);
#pragma unroll
            for (int mm = 0; mm < 2; mm++) {
                const int m = mh * 2 + mm;
                f32x4 acc = (f32x4){0.f, 0.f, 0.f, 0.f};
#pragma unroll
                for (int ks = 0; ks < 8; ks++)
                    acc = __builtin_amdgcn_mfma_f32_16x16x32_bf16(wA[ks], xa[mm][ks], acc, 0, 0, 0);
                bf16x4_t hv = { (bf16_t)fmaxf(acc[0] + bv.x, 0.f),
                                (bf16_t)fmaxf(acc[1] + bv.y, 0.f),
                                (bf16_t)fmaxf(acc[2] + bv.z, 0.f),
                                (bf16_t)fmaxf(acc[3] + bv.w, 0.f) };
                *(bf16x4_t*)swzp<7>(h1, m * 16 + c, fg * 32 + q * 8) = hv;
            }
        }
        // L5(e-1): h4 -> oacc
        if (e > 0) do_l5(e - 1);
        __syncthreads();
    }

    // ---- epilogue: L4(31) -> h4 ; L5(31) -> oacc ----
    {
#pragma unroll
        for (int ks = 0; ks < 2; ks++)
            wE[ks] = *(const bf16x8*)(Wf + (size_t)31 * 81920 + 73728 + ((size_t)(w * 2 + ks) * 64 + lane) * 8);
        const float4 bv = *(const float4*)(b4 + (size_t)31 * H1D + fg * 16 + q * 4);
#pragma unroll
        for (int mm = 0; mm < 2; mm++) {
            const int m = mh * 2 + mm;
            f32x4 acc = (f32x4){0.f, 0.f, 0.f, 0.f};
#pragma unroll
            for (int ks = 0; ks < 4; ks++) {
                bf16x8 ha = *(const bf16x8*)swzp<8>(h3, m * 16 + c, ks * 64 + q * 16);
                acc = __builtin_amdgcn_mfma_f32_16x16x32_bf16(wD[ks], ha, acc, 0, 0, 0);
            }
            bf16x4_t hv = { (bf16_t)fmaxf(acc[0] + bv.x, 0.f),
                            (bf16_t)fmaxf(acc[1] + bv.y, 0.f),
                            (bf16_t)fmaxf(acc[2] + bv.z, 0.f),
                            (bf16_t)fmaxf(acc[3] + bv.w, 0.f) };
            *(bf16x4_t*)swzp<7>(h4, m * 16 + c, fg * 32 + q * 8) = hv;
        }
        __syncthreads();
        do_l5(NE - 1);
    }

    // ---- store: lane owns rows m*16+c, cols w*16 + q*4 .. +3 ----
#pragma unroll
    for (int m = 0; m < 4; m++)
        *(float4*)(out + (size_t)(b0 + m * 16 + c) * NOUT + w * 16 + q * 4) =
            (float4){oacc[m][0], oacc[m][1], oacc[m][2], oacc[m][3]};
}

extern "C" void kernel_launch(void* const* d_in, const int* in_sizes, int n_in,
                              void* d_out, int out_size, void* d_ws, size_t ws_size,
                              hipStream_t stream)
{
    (void)in_sizes; (void)n_in; (void)out_size; (void)ws_size;
    const float* x  = (const float*)d_in[0];
    const float* Wg = (const float*)d_in[1];
    const float* bg = (const float*)d_in[2];
    const float* W1 = (const float*)d_in[3];
    const float* b1 = (const float*)d_in[4];
    const float* W2 = (const float*)d_in[5];
    const float* b2 = (const float*)d_in[6];
    const float* W3 = (const float*)d_in[7];
    const float* b3 = (const float*)d_in[8];
    const float* W4 = (const float*)d_in[9];
    const float* b4 = (const float*)d_in[10];
    const float* W5 = (const float*)d_in[11];
    const float* b5 = (const float*)d_in[12];

    char* ws = (char*)d_ws;
    bf16_t* Wf  = (bf16_t*)(ws + OFF_WF);
    bf16_t* Wgf = (bf16_t*)(ws + OFF_WGF);
    float*  outp = (float*)d_out;

    build_frags<<<dim3(1284), dim3(256), 0, stream>>>(W1, W2, W3, W4, W5, Wg, Wf, Wgf);
    moe_main<<<dim3(BB / 64), dim3(512), 0, stream>>>(x, Wf, Wgf, bg,
                                                      b1, b2, b3, b4, b5, outp);
}

// Round 4
// 249.859 us; speedup vs baseline: 1.1459x; 1.1459x over previous
//
#include <hip/hip_runtime.h>

// Problem constants
#define BB      16384
#define IN_DIM  256
#define NE      32
#define H1D     64
#define H2D     256
#define H3D     128
#define NOUT    128

typedef __bf16 bf16_t;
typedef __bf16 bf16x4_t __attribute__((ext_vector_type(4)));
typedef __bf16 bf16x8  __attribute__((ext_vector_type(8)));
typedef float  f32x4   __attribute__((ext_vector_type(4)));

// ---- workspace: fragment-ordered bf16 weights ----
// Per expert, 160 "sets" of 64 lanes x 16B, contiguous in set order:
//   sets [0,32):   L1  (tile 0..3, ks 0..7)   K=256, N=64
//   sets [32,64):  L2  (tile 0..15, ks 0..1)  K=64,  N=256
//   sets [64,128): L3  (tile 0..7,  ks 0..7)  K=256, N=128
//   sets [128,144):L4  (tile 0..3,  ks 0..3)  K=128, N=64
//   sets [144,160):L5  (tile 0..7,  ks 0..1)  K=64,  N=128
// frag elem: dst[(set*64+lane)*8 + j] = W[k0+j][tile*16+(lane&15)], k0=ks*32+(lane>>4)*8
#define OFF_WF   ((size_t)0)
#define OFF_WGF  ((size_t)NE * 81920 * 2)     // Wg frags: 16 sets = 16 KB

// ---- prep: one thread per fragment (verified round 3) ----
__global__ __launch_bounds__(256) void build_frags(
    const float* __restrict__ W1, const float* __restrict__ W2,
    const float* __restrict__ W3, const float* __restrict__ W4,
    const float* __restrict__ W5, const float* __restrict__ Wg,
    bf16_t* __restrict__ Wf, bf16_t* __restrict__ Wgf)
{
    const int g    = blockIdx.x * 256 + threadIdx.x;
    const int lane = g & 63;
    const int set  = g >> 6;            // 0 .. 5135
    const float* src; bf16_t* dst; int N, t, ks;
    if (set < 5120) {
        const int e = set / 160;
        const int s = set % 160;
        dst = Wf + (size_t)e * 81920 + ((size_t)s * 64 + lane) * 8;
        if (s < 32)       { t = s >> 3;         ks = s & 7;         N = 64;  src = W1 + (size_t)e * 16384; }
        else if (s < 64)  { t = (s - 32) >> 1;  ks = (s - 32) & 1;  N = 256; src = W2 + (size_t)e * 16384; }
        else if (s < 128) { t = (s - 64) >> 3;  ks = (s - 64) & 7;  N = 128; src = W3 + (size_t)e * 32768; }
        else if (s < 144) { t = (s - 128) >> 2; ks = (s - 128) & 3; N = 64;  src = W4 + (size_t)e * 8192;  }
        else              { t = (s - 144) >> 1; ks = (s - 144) & 1; N = 128; src = W5 + (size_t)e * 8192;  }
    } else {
        const int s = set - 5120;
        t = s >> 3; ks = s & 7; N = 32; src = Wg;
        dst = Wgf + ((size_t)s * 64 + lane) * 8;
    }
    const int f  = t * 16 + (lane & 15);
    const int k0 = ks * 32 + (lane >> 4) * 8;
    bf16x8 o;
#pragma unroll
    for (int j = 0; j < 8; j++) o[j] = (bf16_t)src[(size_t)(k0 + j) * N + f];
    *(bf16x8*)dst = o;
}

// ---- swizzled LDS addressing: 16B-granule XOR with row&7 (bank-balanced) ----
template<int RS>
__device__ __forceinline__ void* swzp(char* base, int row, int byteoff) {
    const int g = byteoff >> 4;
    return (void*)(base + ((row << RS) | ((g ^ (row & 7)) << 4) | (byteoff & 15)));
}

// ---- LDS carve: 64-row tile ----
#define L_H1   0          // h1 [64][128B]  RS=7   8 KB
#define L_SX   8192       // x  [64][512B]  RS=9  32 KB
#define L_H2   40960      // h2 [64][512B]  RS=9  32 KB
#define L_H3   73728      // h3 [64][256B]  RS=8  16 KB (alias gating logits [64][36] f32)
#define L_H4   90112      // h4 [64][128B]  RS=7   8 KB
#define L_SG   98304      // g  [32e][64b] f32     8 KB
#define L_TOT  106496

// ---- main: 64-row tile, 8 waves, 256 blocks; 2 barriers/expert; no xa regs ----
__global__ __launch_bounds__(512) void moe_main(
    const float* __restrict__ x, const bf16_t* __restrict__ Wf,
    const bf16_t* __restrict__ Wgf, const float* __restrict__ bg,
    const float* __restrict__ b1, const float* __restrict__ b2,
    const float* __restrict__ b3, const float* __restrict__ b4,
    const float* __restrict__ b5, float* __restrict__ out)
{
    __shared__ __align__(16) char lds[L_TOT];
    char* sX = lds + L_SX;
    char* h1 = lds + L_H1;
    char* h2 = lds + L_H2;
    char* h3 = lds + L_H3;
    char* h4 = lds + L_H4;
    float* sG = (float*)(lds + L_SG);

    const int tid  = threadIdx.x;
    const int w    = tid >> 6;
    const int lane = tid & 63;
    const int c    = lane & 15;
    const int q    = lane >> 4;
    const int fg   = w & 3;             // f-tile group (L1/L4), L3 tile pair base/2
    const int mh   = w >> 2;            // m-half (L1/L4/L3)
    const int b0   = blockIdx.x * 64;

    bf16x8 wA[8], wB[2][2], wD[4], wE[2];

    // early issue: wA(0) [L1 tile fg], wB(0) [L2 tiles w*2..+1]
#pragma unroll
    for (int ks = 0; ks < 8; ks++)
        wA[ks] = *(const bf16x8*)(Wf + ((size_t)(fg * 8 + ks) * 64 + lane) * 8);
#pragma unroll
    for (int nt = 0; nt < 2; nt++)
#pragma unroll
        for (int ks = 0; ks < 2; ks++)
            wB[nt][ks] = *(const bf16x8*)(Wf + 16384 + ((size_t)((w * 2 + nt) * 2 + ks) * 64 + lane) * 8);

    // ---- stage x: 64x256 fp32 -> bf16, swizzled ----
    {
        const int r  = tid >> 3;
        const int c0 = (tid & 7) * 32;
        const float* sp = x + (size_t)(b0 + r) * IN_DIM + c0;
#pragma unroll
        for (int jj = 0; jj < 4; jj++) {
            const float4 v0 = *(const float4*)(sp + jj * 8);
            const float4 v1 = *(const float4*)(sp + jj * 8 + 4);
            bf16x8 o = { (bf16_t)v0.x, (bf16_t)v0.y, (bf16_t)v0.z, (bf16_t)v0.w,
                         (bf16_t)v1.x, (bf16_t)v1.y, (bf16_t)v1.z, (bf16_t)v1.w };
            *(bf16x8*)swzp<9>(sX, r, c0 * 2 + jj * 16) = o;
        }
    }
    __syncthreads();

    // ---- gating logits -> h3 alias [64][36] f32 ----
    {
        const int t = w & 1, m = w >> 1;
        f32x4 acc = (f32x4){0.f, 0.f, 0.f, 0.f};
#pragma unroll
        for (int ks = 0; ks < 8; ks++) {
            bf16x8 xv = *(const bf16x8*)swzp<9>(sX, m * 16 + c, ks * 64 + q * 16);
            bf16x8 wg = *(const bf16x8*)(Wgf + ((size_t)(t * 8 + ks) * 64 + lane) * 8);
            acc = __builtin_amdgcn_mfma_f32_16x16x32_bf16(wg, xv, acc, 0, 0, 0);
        }
        const float4 bgv = *(const float4*)(bg + t * 16 + q * 4);
        float* sLgF = (float*)h3;
        *(float4*)(sLgF + (size_t)(m * 16 + c) * 36 + t * 16 + q * 4) =
            (float4){acc[0] + bgv.x, acc[1] + bgv.y, acc[2] + bgv.z, acc[3] + bgv.w};
    }
    __syncthreads();

    // ---- softmax -> sG ; L1(0): sX -> h1 ----
    {
        const int r = tid >> 3;
        const int j = tid & 7;
        const float* sLgF = (const float*)h3;
        float4 l = *(const float4*)(sLgF + (size_t)r * 36 + j * 4);
        float mx = fmaxf(fmaxf(l.x, l.y), fmaxf(l.z, l.w));
#pragma unroll
        for (int off = 1; off < 8; off <<= 1) mx = fmaxf(mx, __shfl_xor(mx, off));
        float e0 = __expf(l.x - mx), e1 = __expf(l.y - mx),
              e2 = __expf(l.z - mx), e3 = __expf(l.w - mx);
        float sm = e0 + e1 + e2 + e3;
#pragma unroll
        for (int off = 1; off < 8; off <<= 1) sm += __shfl_xor(sm, off);
        const float rs = 1.f / sm;
        sG[(j * 4 + 0) * 64 + r] = e0 * rs;
        sG[(j * 4 + 1) * 64 + r] = e1 * rs;
        sG[(j * 4 + 2) * 64 + r] = e2 * rs;
        sG[(j * 4 + 3) * 64 + r] = e3 * rs;
    }
    {
        const float4 bv = *(const float4*)(b1 + fg * 16 + q * 4);
#pragma unroll
        for (int mm = 0; mm < 2; mm++) {
            const int m = mh * 2 + mm;
            f32x4 acc = (f32x4){0.f, 0.f, 0.f, 0.f};
#pragma unroll
            for (int ks = 0; ks < 8; ks++) {
                bf16x8 xv = *(const bf16x8*)swzp<9>(sX, m * 16 + c, ks * 64 + q * 16);
                acc = __builtin_amdgcn_mfma_f32_16x16x32_bf16(wA[ks], xv, acc, 0, 0, 0);
            }
            bf16x4_t hv = { (bf16_t)fmaxf(acc[0] + bv.x, 0.f),
                            (bf16_t)fmaxf(acc[1] + bv.y, 0.f),
                            (bf16_t)fmaxf(acc[2] + bv.z, 0.f),
                            (bf16_t)fmaxf(acc[3] + bv.w, 0.f) };
            *(bf16x4_t*)swzp<7>(h1, m * 16 + c, fg * 32 + q * 8) = hv;
        }
    }
    __syncthreads();

    float oacc[4][4];
#pragma unroll
    for (int m = 0; m < 4; m++)
#pragma unroll
        for (int r = 0; r < 4; r++) oacc[m][r] = 0.f;

    auto do_l5 = [&](int ep) {
        const float4 bv = *(const float4*)(b5 + (size_t)ep * NOUT + w * 16 + q * 4);
#pragma unroll
        for (int m = 0; m < 4; m++) {
            f32x4 acc = (f32x4){0.f, 0.f, 0.f, 0.f};
#pragma unroll
            for (int ks = 0; ks < 2; ks++) {
                bf16x8 ha = *(const bf16x8*)swzp<7>(h4, m * 16 + c, ks * 64 + q * 16);
                acc = __builtin_amdgcn_mfma_f32_16x16x32_bf16(wE[ks], ha, acc, 0, 0, 0);
            }
            const float gv = sG[ep * 64 + m * 16 + c];
            oacc[m][0] += gv * (acc[0] + bv.x);
            oacc[m][1] += gv * (acc[1] + bv.y);
            oacc[m][2] += gv * (acc[2] + bv.z);
            oacc[m][3] += gv * (acc[3] + bv.w);
        }
    };

    auto do_l4 = [&](int ep) {   // h3 -> h4, tile fg, rows mh half
        const float4 bv = *(const float4*)(b4 + (size_t)ep * H1D + fg * 16 + q * 4);
#pragma unroll
        for (int mm = 0; mm < 2; mm++) {
            const int m = mh * 2 + mm;
            f32x4 acc = (f32x4){0.f, 0.f, 0.f, 0.f};
#pragma unroll
            for (int ks = 0; ks < 4; ks++) {
                bf16x8 ha = *(const bf16x8*)swzp<8>(h3, m * 16 + c, ks * 64 + q * 16);
                acc = __builtin_amdgcn_mfma_f32_16x16x32_bf16(wD[ks], ha, acc, 0, 0, 0);
            }
            bf16x4_t hv = { (bf16_t)fmaxf(acc[0] + bv.x, 0.f),
                            (bf16_t)fmaxf(acc[1] + bv.y, 0.f),
                            (bf16_t)fmaxf(acc[2] + bv.z, 0.f),
                            (bf16_t)fmaxf(acc[3] + bv.w, 0.f) };
            *(bf16x4_t*)swzp<7>(h4, m * 16 + c, fg * 32 + q * 8) = hv;
        }
    };

    // ---- expert loop: X = {L2(e), L4(e-1)}, Y = {L3(e), L1(e+1), L5(e-1)} ----
    for (int e = 0; e < NE; e++) {
        const bf16_t* We  = Wf + (size_t)e * 81920;
        const bf16_t* Wen = Wf + (size_t)((e + 1) & 31) * 81920;
        const bf16_t* Wep = Wf + (size_t)((e - 1) & 31) * 81920;

        // ---- X phase: prefetch wA(e+1), wE(e-1) ----
#pragma unroll
        for (int ks = 0; ks < 8; ks++)
            wA[ks] = *(const bf16x8*)(Wen + ((size_t)(fg * 8 + ks) * 64 + lane) * 8);
#pragma unroll
        for (int ks = 0; ks < 2; ks++)
            wE[ks] = *(const bf16x8*)(Wep + 73728 + ((size_t)(w * 2 + ks) * 64 + lane) * 8);

        // L2(e): h1 -> h2 (tiles w*2..+1, all m)
        {
            float4 bv[2];
#pragma unroll
            for (int nt = 0; nt < 2; nt++)
                bv[nt] = *(const float4*)(b2 + (size_t)e * H2D + (w * 2 + nt) * 16 + q * 4);
#pragma unroll
            for (int m = 0; m < 4; m++) {
                bf16x8 ha[2];
#pragma unroll
                for (int ks = 0; ks < 2; ks++)
                    ha[ks] = *(const bf16x8*)swzp<7>(h1, m * 16 + c, ks * 64 + q * 16);
                f32x4 acc[2];
#pragma unroll
                for (int nt = 0; nt < 2; nt++) acc[nt] = (f32x4){0.f, 0.f, 0.f, 0.f};
#pragma unroll
                for (int nt = 0; nt < 2; nt++)
#pragma unroll
                    for (int ks = 0; ks < 2; ks++)
                        acc[nt] = __builtin_amdgcn_mfma_f32_16x16x32_bf16(wB[nt][ks], ha[ks], acc[nt], 0, 0, 0);
#pragma unroll
                for (int nt = 0; nt < 2; nt++) {
                    bf16x4_t hv = { (bf16_t)fmaxf(acc[nt][0] + bv[nt].x, 0.f),
                                    (bf16_t)fmaxf(acc[nt][1] + bv[nt].y, 0.f),
                                    (bf16_t)fmaxf(acc[nt][2] + bv[nt].z, 0.f),
                                    (bf16_t)fmaxf(acc[nt][3] + bv[nt].w, 0.f) };
                    *(bf16x4_t*)swzp<9>(h2, m * 16 + c, (w * 2 + nt) * 32 + q * 8) = hv;
                }
            }
        }
        // L4(e-1): h3 -> h4 (wD prefetched in Y(e-1))
        if (e > 0) do_l4(e - 1);
        __syncthreads();

        // ---- Y phase: load wC(e) [2 tiles]; prefetch wB(e+1), wD(e) ----
        bf16x8 wC[2][8];
#pragma unroll
        for (int jt = 0; jt < 2; jt++)
#pragma unroll
            for (int ks = 0; ks < 8; ks++)
                wC[jt][ks] = *(const bf16x8*)(We + 32768 + ((size_t)((fg * 2 + jt) * 8 + ks) * 64 + lane) * 8);
#pragma unroll
        for (int nt = 0; nt < 2; nt++)
#pragma unroll
            for (int ks = 0; ks < 2; ks++)
                wB[nt][ks] = *(const bf16x8*)(Wen + 16384 + ((size_t)((w * 2 + nt) * 2 + ks) * 64 + lane) * 8);
#pragma unroll
        for (int ks = 0; ks < 4; ks++)
            wD[ks] = *(const bf16x8*)(We + 65536 + ((size_t)(fg * 4 + ks) * 64 + lane) * 8);

        // L3(e): h2 -> h3; m-split (rows mh half), 2 f-tiles per wave, B read once
        {
            float4 bv[2];
#pragma unroll
            for (int jt = 0; jt < 2; jt++)
                bv[jt] = *(const float4*)(b3 + (size_t)e * H3D + (fg * 2 + jt) * 16 + q * 4);
#pragma unroll
            for (int mm = 0; mm < 2; mm++) {
                const int m = mh * 2 + mm;
                f32x4 acc[2];
#pragma unroll
                for (int jt = 0; jt < 2; jt++) acc[jt] = (f32x4){0.f, 0.f, 0.f, 0.f};
#pragma unroll
                for (int ks = 0; ks < 8; ks++) {
                    bf16x8 ha = *(const bf16x8*)swzp<9>(h2, m * 16 + c, ks * 64 + q * 16);
#pragma unroll
                    for (int jt = 0; jt < 2; jt++)
                        acc[jt] = __builtin_amdgcn_mfma_f32_16x16x32_bf16(wC[jt][ks], ha, acc[jt], 0, 0, 0);
                }
#pragma unroll
                for (int jt = 0; jt < 2; jt++) {
                    bf16x4_t hv = { (bf16_t)fmaxf(acc[jt][0] + bv[jt].x, 0.f),
                                    (bf16_t)fmaxf(acc[jt][1] + bv[jt].y, 0.f),
                                    (bf16_t)fmaxf(acc[jt][2] + bv[jt].z, 0.f),
                                    (bf16_t)fmaxf(acc[jt][3] + bv[jt].w, 0.f) };
                    *(bf16x4_t*)swzp<8>(h3, m * 16 + c, (fg * 2 + jt) * 32 + q * 8) = hv;
                }
            }
        }
        // L1(e+1): sX -> h1
        if (e < NE - 1) {
            const float4 bv = *(const float4*)(b1 + (size_t)(e + 1) * H1D + fg * 16 + q * 4);
#pragma unroll
            for (int mm = 0; mm < 2; mm++) {
                const int m = mh * 2 + mm;
                f32x4 acc = (f32x4){0.f, 0.f, 0.f, 0.f};
#pragma unroll
                for (int ks = 0; ks < 8; ks++) {
                    bf16x8 xv = *(const bf16x8*)swzp<9>(sX, m * 16 + c, ks * 64 + q * 16);
                    acc = __builtin_amdgcn_mfma_f32_16x16x32_bf16(wA[ks], xv, acc, 0, 0, 0);
                }
                bf16x4_t hv = { (bf16_t)fmaxf(acc[0] + bv.x, 0.f),
                                (bf16_t)fmaxf(acc[1] + bv.y, 0.f),
                                (bf16_t)fmaxf(acc[2] + bv.z, 0.f),
                                (bf16_t)fmaxf(acc[3] + bv.w, 0.f) };
                *(bf16x4_t*)swzp<7>(h1, m * 16 + c, fg * 32 + q * 8) = hv;
            }
        }
        // L5(e-1): h4 -> oacc
        if (e > 0) do_l5(e - 1);
        __syncthreads();
    }

    // ---- epilogue: L4(31) (wD prefetched in Y(31)); then L5(31) ----
    do_l4(NE - 1);
#pragma unroll
    for (int ks = 0; ks < 2; ks++)
        wE[ks] = *(const bf16x8*)(Wf + (size_t)31 * 81920 + 73728 + ((size_t)(w * 2 + ks) * 64 + lane) * 8);
    __syncthreads();
    do_l5(NE - 1);

    // ---- store: lane owns rows m*16+c, cols w*16 + q*4 .. +3 ----
#pragma unroll
    for (int m = 0; m < 4; m++)
        *(float4*)(out + (size_t)(b0 + m * 16 + c) * NOUT + w * 16 + q * 4) =
            (float4){oacc[m][0], oacc[m][1], oacc[m][2], oacc[m][3]};
}

extern "C" void kernel_launch(void* const* d_in, const int* in_sizes, int n_in,
                              void* d_out, int out_size, void* d_ws, size_t ws_size,
                              hipStream_t stream)
{
    (void)in_sizes; (void)n_in; (void)out_size; (void)ws_size;
    const float* x  = (const float*)d_in[0];
    const float* Wg = (const float*)d_in[1];
    const float* bg = (const float*)d_in[2];
    const float* W1 = (const float*)d_in[3];
    const float* b1 = (const float*)d_in[4];
    const float* W2 = (const float*)d_in[5];
    const float* b2 = (const float*)d_in[6];
    const float* W3 = (const float*)d_in[7];
    const float* b3 = (const float*)d_in[8];
    const float* W4 = (const float*)d_in[9];
    const float* b4 = (const float*)d_in[10];
    const float* W5 = (const float*)d_in[11];
    const float* b5 = (const float*)d_in[12];

    char* ws = (char*)d_ws;
    bf16_t* Wf  = (bf16_t*)(ws + OFF_WF);
    bf16_t* Wgf = (bf16_t*)(ws + OFF_WGF);
    float*  outp = (float*)d_out;

    build_frags<<<dim3(1284), dim3(256), 0, stream>>>(W1, W2, W3, W4, W5, Wg, Wf, Wgf);
    moe_main<<<dim3(BB / 64), dim3(512), 0, stream>>>(x, Wf, Wgf, bg,
                                                      b1, b2, b3, b4, b5, outp);
}

// Round 6
// 226.277 us; speedup vs baseline: 1.2654x; 1.1042x over previous
//
#include <hip/hip_runtime.h>

// Problem constants
#define BB      16384
#define IN_DIM  256
#define NE      32
#define H1D     64
#define H2D     256
#define H3D     128
#define NOUT    128

typedef __bf16 bf16_t;
typedef __bf16 bf16x4_t __attribute__((ext_vector_type(4)));
typedef __bf16 bf16x8  __attribute__((ext_vector_type(8)));
typedef float  f32x4   __attribute__((ext_vector_type(4)));

// ---- workspace: fragment-ordered bf16 weights ----
// Per expert, 160 "sets" of 64 lanes x 16B, contiguous in set order:
//   sets [0,32):   L1  (tile 0..3, ks 0..7)   K=256, N=64
//   sets [32,64):  L2  (tile 0..15, ks 0..1)  K=64,  N=256
//   sets [64,128): L3  (tile 0..7,  ks 0..7)  K=256, N=128
//   sets [128,144):L4  (tile 0..3,  ks 0..3)  K=128, N=64
//   sets [144,160):L5  (tile 0..7,  ks 0..1)  K=64,  N=128
// frag elem: dst[(set*64+lane)*8 + j] = W[k0+j][tile*16+(lane&15)], k0=ks*32+(lane>>4)*8
#define OFF_WF   ((size_t)0)
#define OFF_WGF  ((size_t)NE * 81920 * 2)     // Wg frags: 16 sets = 16 KB

// ---- prep: one thread per fragment (verified round 3/4) ----
__global__ __launch_bounds__(256) void build_frags(
    const float* __restrict__ W1, const float* __restrict__ W2,
    const float* __restrict__ W3, const float* __restrict__ W4,
    const float* __restrict__ W5, const float* __restrict__ Wg,
    bf16_t* __restrict__ Wf, bf16_t* __restrict__ Wgf)
{
    const int g    = blockIdx.x * 256 + threadIdx.x;
    const int lane = g & 63;
    const int set  = g >> 6;            // 0 .. 5135
    const float* src; bf16_t* dst; int N, t, ks;
    if (set < 5120) {
        const int e = set / 160;
        const int s = set % 160;
        dst = Wf + (size_t)e * 81920 + ((size_t)s * 64 + lane) * 8;
        if (s < 32)       { t = s >> 3;         ks = s & 7;         N = 64;  src = W1 + (size_t)e * 16384; }
        else if (s < 64)  { t = (s - 32) >> 1;  ks = (s - 32) & 1;  N = 256; src = W2 + (size_t)e * 16384; }
        else if (s < 128) { t = (s - 64) >> 3;  ks = (s - 64) & 7;  N = 128; src = W3 + (size_t)e * 32768; }
        else if (s < 144) { t = (s - 128) >> 2; ks = (s - 128) & 3; N = 64;  src = W4 + (size_t)e * 8192;  }
        else              { t = (s - 144) >> 1; ks = (s - 144) & 1; N = 128; src = W5 + (size_t)e * 8192;  }
    } else {
        const int s = set - 5120;
        t = s >> 3; ks = s & 7; N = 32; src = Wg;
        dst = Wgf + ((size_t)s * 64 + lane) * 8;
    }
    const int f  = t * 16 + (lane & 15);
    const int k0 = ks * 32 + (lane >> 4) * 8;
    bf16x8 o;
#pragma unroll
    for (int j = 0; j < 8; j++) o[j] = (bf16_t)src[(size_t)(k0 + j) * N + f];
    *(bf16x8*)dst = o;
}

// ---- swizzled LDS addressing: 16B-granule XOR with row&7 (bank-balanced) ----
template<int RS>
__device__ __forceinline__ void* swzp(char* base, int row, int byteoff) {
    const int g = byteoff >> 4;
    return (void*)(base + ((row << RS) | ((g ^ (row & 7)) << 4) | (byteoff & 15)));
}

// ---- LDS carve: 64-row tile ----
#define L_H1   0          // h1 [64][128B]  RS=7   8 KB
#define L_SX   8192       // x  [64][512B]  RS=9  32 KB
#define L_H2   40960      // h2 [64][512B]  RS=9  32 KB
#define L_H3   73728      // h3 [64][256B]  RS=8  16 KB (alias gating logits [64][36] f32)
#define L_H4   90112      // h4 [64][128B]  RS=7   8 KB
#define L_SG   98304      // g  [32e][64b] f32     8 KB
#define L_TOT  106496

// ---- main: 64-row tile, 8 waves, 256 blocks; 2 barriers/expert,
//      strict one-phase-ahead weight prefetch (nothing exposed) ----
__global__ __launch_bounds__(512) void moe_main(
    const float* __restrict__ x, const bf16_t* __restrict__ Wf,
    const bf16_t* __restrict__ Wgf, const float* __restrict__ bg,
    const float* __restrict__ b1, const float* __restrict__ b2,
    const float* __restrict__ b3, const float* __restrict__ b4,
    const float* __restrict__ b5, float* __restrict__ out)
{
    __shared__ __align__(16) char lds[L_TOT];
    char* sX = lds + L_SX;
    char* h1 = lds + L_H1;
    char* h2 = lds + L_H2;
    char* h3 = lds + L_H3;
    char* h4 = lds + L_H4;
    float* sG = (float*)(lds + L_SG);

    const int tid  = threadIdx.x;
    const int w    = tid >> 6;
    const int lane = tid & 63;
    const int c    = lane & 15;
    const int q    = lane >> 4;
    const int fg   = w & 3;             // f-tile for L1/L4
    const int mh   = w >> 2;            // m-half for L1/L4
    const int b0   = blockIdx.x * 64;

    bf16x8 wA[8], wB[2][2], wC[8], wD[4], wE[2];

    // early issue: wA(0) [L1 tile fg], wB(0) [L2 tiles w*2..+1]
#pragma unroll
    for (int ks = 0; ks < 8; ks++)
        wA[ks] = *(const bf16x8*)(Wf + ((size_t)(fg * 8 + ks) * 64 + lane) * 8);
#pragma unroll
    for (int nt = 0; nt < 2; nt++)
#pragma unroll
        for (int ks = 0; ks < 2; ks++)
            wB[nt][ks] = *(const bf16x8*)(Wf + 16384 + ((size_t)((w * 2 + nt) * 2 + ks) * 64 + lane) * 8);

    // ---- stage x: 64x256 fp32 -> bf16, swizzled ----
    {
        const int r  = tid >> 3;
        const int c0 = (tid & 7) * 32;
        const float* sp = x + (size_t)(b0 + r) * IN_DIM + c0;
#pragma unroll
        for (int jj = 0; jj < 4; jj++) {
            const float4 v0 = *(const float4*)(sp + jj * 8);
            const float4 v1 = *(const float4*)(sp + jj * 8 + 4);
            bf16x8 o = { (bf16_t)v0.x, (bf16_t)v0.y, (bf16_t)v0.z, (bf16_t)v0.w,
                         (bf16_t)v1.x, (bf16_t)v1.y, (bf16_t)v1.z, (bf16_t)v1.w };
            *(bf16x8*)swzp<9>(sX, r, c0 * 2 + jj * 16) = o;
        }
    }
    __syncthreads();

    // ---- gating logits -> h3 alias [64][36] f32 ----
    {
        const int t = w & 1, m = w >> 1;
        f32x4 acc = (f32x4){0.f, 0.f, 0.f, 0.f};
#pragma unroll
        for (int ks = 0; ks < 8; ks++) {
            bf16x8 xv = *(const bf16x8*)swzp<9>(sX, m * 16 + c, ks * 64 + q * 16);
            bf16x8 wg = *(const bf16x8*)(Wgf + ((size_t)(t * 8 + ks) * 64 + lane) * 8);
            acc = __builtin_amdgcn_mfma_f32_16x16x32_bf16(wg, xv, acc, 0, 0, 0);
        }
        const float4 bgv = *(const float4*)(bg + t * 16 + q * 4);
        float* sLgF = (float*)h3;
        *(float4*)(sLgF + (size_t)(m * 16 + c) * 36 + t * 16 + q * 4) =
            (float4){acc[0] + bgv.x, acc[1] + bgv.y, acc[2] + bgv.z, acc[3] + bgv.w};
    }
    __syncthreads();

    // ---- softmax -> sG ; L1(0): sX -> h1 ----
    {
        const int r = tid >> 3;
        const int j = tid & 7;
        const float* sLgF = (const float*)h3;
        float4 l = *(const float4*)(sLgF + (size_t)r * 36 + j * 4);
        float mx = fmaxf(fmaxf(l.x, l.y), fmaxf(l.z, l.w));
#pragma unroll
        for (int off = 1; off < 8; off <<= 1) mx = fmaxf(mx, __shfl_xor(mx, off));
        float e0 = __expf(l.x - mx), e1 = __expf(l.y - mx),
              e2 = __expf(l.z - mx), e3 = __expf(l.w - mx);
        float sm = e0 + e1 + e2 + e3;
#pragma unroll
        for (int off = 1; off < 8; off <<= 1) sm += __shfl_xor(sm, off);
        const float rs = 1.f / sm;
        sG[(j * 4 + 0) * 64 + r] = e0 * rs;
        sG[(j * 4 + 1) * 64 + r] = e1 * rs;
        sG[(j * 4 + 2) * 64 + r] = e2 * rs;
        sG[(j * 4 + 3) * 64 + r] = e3 * rs;
    }
    {
        const float4 bv = *(const float4*)(b1 + fg * 16 + q * 4);
#pragma unroll
        for (int mm = 0; mm < 2; mm++) {
            const int m = mh * 2 + mm;
            f32x4 acc = (f32x4){0.f, 0.f, 0.f, 0.f};
#pragma unroll
            for (int ks = 0; ks < 8; ks++) {
                bf16x8 xv = *(const bf16x8*)swzp<9>(sX, m * 16 + c, ks * 64 + q * 16);
                acc = __builtin_amdgcn_mfma_f32_16x16x32_bf16(wA[ks], xv, acc, 0, 0, 0);
            }
            bf16x4_t hv = { (bf16_t)fmaxf(acc[0] + bv.x, 0.f),
                            (bf16_t)fmaxf(acc[1] + bv.y, 0.f),
                            (bf16_t)fmaxf(acc[2] + bv.z, 0.f),
                            (bf16_t)fmaxf(acc[3] + bv.w, 0.f) };
            *(bf16x4_t*)swzp<7>(h1, m * 16 + c, fg * 32 + q * 8) = hv;
        }
    }
    __syncthreads();

    float oacc[4][4];
#pragma unroll
    for (int m = 0; m < 4; m++)
#pragma unroll
        for (int r = 0; r < 4; r++) oacc[m][r] = 0.f;

    auto do_l5 = [&](int ep) {   // h4 -> oacc, f-tile w, all m (wE prefetched)
        const float4 bv = *(const float4*)(b5 + (size_t)ep * NOUT + w * 16 + q * 4);
#pragma unroll
        for (int m = 0; m < 4; m++) {
            f32x4 acc = (f32x4){0.f, 0.f, 0.f, 0.f};
#pragma unroll
            for (int ks = 0; ks < 2; ks++) {
                bf16x8 ha = *(const bf16x8*)swzp<7>(h4, m * 16 + c, ks * 64 + q * 16);
                acc = __builtin_amdgcn_mfma_f32_16x16x32_bf16(wE[ks], ha, acc, 0, 0, 0);
            }
            const float gv = sG[ep * 64 + m * 16 + c];
            oacc[m][0] += gv * (acc[0] + bv.x);
            oacc[m][1] += gv * (acc[1] + bv.y);
            oacc[m][2] += gv * (acc[2] + bv.z);
            oacc[m][3] += gv * (acc[3] + bv.w);
        }
    };

    auto do_l4 = [&](int ep) {   // h3 -> h4, f-tile fg, rows mh half (wD prefetched)
        const float4 bv = *(const float4*)(b4 + (size_t)ep * H1D + fg * 16 + q * 4);
#pragma unroll
        for (int mm = 0; mm < 2; mm++) {
            const int m = mh * 2 + mm;
            f32x4 acc = (f32x4){0.f, 0.f, 0.f, 0.f};
#pragma unroll
            for (int ks = 0; ks < 4; ks++) {
                bf16x8 ha = *(const bf16x8*)swzp<8>(h3, m * 16 + c, ks * 64 + q * 16);
                acc = __builtin_amdgcn_mfma_f32_16x16x32_bf16(wD[ks], ha, acc, 0, 0, 0);
            }
            bf16x4_t hv = { (bf16_t)fmaxf(acc[0] + bv.x, 0.f),
                            (bf16_t)fmaxf(acc[1] + bv.y, 0.f),
                            (bf16_t)fmaxf(acc[2] + bv.z, 0.f),
                            (bf16_t)fmaxf(acc[3] + bv.w, 0.f) };
            *(bf16x4_t*)swzp<7>(h4, m * 16 + c, fg * 32 + q * 8) = hv;
        }
    };

    // ---- expert loop: X = {L2(e), L4(e-1)}, Y = {L3(e), L1(e+1), L5(e-1)} ----
    // Prefetch map (issue -> use, always one phase ahead or covered):
    //   X(e) issues wC(e)   -> L3(e)   in Y(e)   [cross-barrier]
    //   X(e) issues wA(e+1) -> L1(e+1) in Y(e)   [cross-barrier]
    //   Y(e) issues wE(e-1) -> L5(e-1) in Y(e)   [covered by L3+L1 compute]
    //   Y(e) issues wB(e+1) -> L2(e+1) in X(e+1) [cross-barrier]
    //   Y(e) issues wD(e)   -> L4(e)   in X(e+1) [cross-barrier]
    for (int e = 0; e < NE; e++) {
        const bf16_t* We  = Wf + (size_t)e * 81920;
        const bf16_t* Wen = Wf + (size_t)((e + 1) & 31) * 81920;
        const bf16_t* Wep = Wf + (size_t)((e - 1) & 31) * 81920;

        // ---- X phase: issue wC(e), wA(e+1) ----
#pragma unroll
        for (int ks = 0; ks < 8; ks++)
            wC[ks] = *(const bf16x8*)(We + 32768 + ((size_t)(w * 8 + ks) * 64 + lane) * 8);
#pragma unroll
        for (int ks = 0; ks < 8; ks++)
            wA[ks] = *(const bf16x8*)(Wen + ((size_t)(fg * 8 + ks) * 64 + lane) * 8);

        // L2(e): h1 -> h2 (tiles w*2..+1, all m) — wB prefetched in Y(e-1)
        {
            float4 bv[2];
#pragma unroll
            for (int nt = 0; nt < 2; nt++)
                bv[nt] = *(const float4*)(b2 + (size_t)e * H2D + (w * 2 + nt) * 16 + q * 4);
#pragma unroll
            for (int m = 0; m < 4; m++) {
                bf16x8 ha[2];
#pragma unroll
                for (int ks = 0; ks < 2; ks++)
                    ha[ks] = *(const bf16x8*)swzp<7>(h1, m * 16 + c, ks * 64 + q * 16);
                f32x4 acc[2];
#pragma unroll
                for (int nt = 0; nt < 2; nt++) acc[nt] = (f32x4){0.f, 0.f, 0.f, 0.f};
#pragma unroll
                for (int nt = 0; nt < 2; nt++)
#pragma unroll
                    for (int ks = 0; ks < 2; ks++)
                        acc[nt] = __builtin_amdgcn_mfma_f32_16x16x32_bf16(wB[nt][ks], ha[ks], acc[nt], 0, 0, 0);
#pragma unroll
                for (int nt = 0; nt < 2; nt++) {
                    bf16x4_t hv = { (bf16_t)fmaxf(acc[nt][0] + bv[nt].x, 0.f),
                                    (bf16_t)fmaxf(acc[nt][1] + bv[nt].y, 0.f),
                                    (bf16_t)fmaxf(acc[nt][2] + bv[nt].z, 0.f),
                                    (bf16_t)fmaxf(acc[nt][3] + bv[nt].w, 0.f) };
                    *(bf16x4_t*)swzp<9>(h2, m * 16 + c, (w * 2 + nt) * 32 + q * 8) = hv;
                }
            }
        }
        // L4(e-1): h3 -> h4 — wD prefetched in Y(e-1)
        if (e > 0) do_l4(e - 1);
        __syncthreads();

        // ---- Y phase: issue wE(e-1), wB(e+1), wD(e) ----
        if (e > 0) {
#pragma unroll
            for (int ks = 0; ks < 2; ks++)
                wE[ks] = *(const bf16x8*)(Wep + 73728 + ((size_t)(w * 2 + ks) * 64 + lane) * 8);
        }
#pragma unroll
        for (int nt = 0; nt < 2; nt++)
#pragma unroll
            for (int ks = 0; ks < 2; ks++)
                wB[nt][ks] = *(const bf16x8*)(Wen + 16384 + ((size_t)((w * 2 + nt) * 2 + ks) * 64 + lane) * 8);
#pragma unroll
        for (int ks = 0; ks < 4; ks++)
            wD[ks] = *(const bf16x8*)(We + 65536 + ((size_t)(fg * 4 + ks) * 64 + lane) * 8);

        // L3(e): h2 -> h3 (f-tile w, all m) — wC prefetched in X(e)
        {
            const float4 bv = *(const float4*)(b3 + (size_t)e * H3D + w * 16 + q * 4);
#pragma unroll
            for (int m = 0; m < 4; m++) {
                f32x4 acc = (f32x4){0.f, 0.f, 0.f, 0.f};
#pragma unroll
                for (int ks = 0; ks < 8; ks++) {
                    bf16x8 ha = *(const bf16x8*)swzp<9>(h2, m * 16 + c, ks * 64 + q * 16);
                    acc = __builtin_amdgcn_mfma_f32_16x16x32_bf16(wC[ks], ha, acc, 0, 0, 0);
                }
                bf16x4_t hv = { (bf16_t)fmaxf(acc[0] + bv.x, 0.f),
                                (bf16_t)fmaxf(acc[1] + bv.y, 0.f),
                                (bf16_t)fmaxf(acc[2] + bv.z, 0.f),
                                (bf16_t)fmaxf(acc[3] + bv.w, 0.f) };
                *(bf16x4_t*)swzp<8>(h3, m * 16 + c, w * 32 + q * 8) = hv;
            }
        }
        // L1(e+1): sX -> h1 — wA prefetched in X(e)
        if (e < NE - 1) {
            const float4 bv = *(const float4*)(b1 + (size_t)(e + 1) * H1D + fg * 16 + q * 4);
#pragma unroll
            for (int mm = 0; mm < 2; mm++) {
                const int m = mh * 2 + mm;
                f32x4 acc = (f32x4){0.f, 0.f, 0.f, 0.f};
#pragma unroll
                for (int ks = 0; ks < 8; ks++) {
                    bf16x8 xv = *(const bf16x8*)swzp<9>(sX, m * 16 + c, ks * 64 + q * 16);
                    acc = __builtin_amdgcn_mfma_f32_16x16x32_bf16(wA[ks], xv, acc, 0, 0, 0);
                }
                bf16x4_t hv = { (bf16_t)fmaxf(acc[0] + bv.x, 0.f),
                                (bf16_t)fmaxf(acc[1] + bv.y, 0.f),
                                (bf16_t)fmaxf(acc[2] + bv.z, 0.f),
                                (bf16_t)fmaxf(acc[3] + bv.w, 0.f) };
                *(bf16x4_t*)swzp<7>(h1, m * 16 + c, fg * 32 + q * 8) = hv;
            }
        }
        // L5(e-1): h4 -> oacc — wE covered by L3+L1 above
        if (e > 0) do_l5(e - 1);
        __syncthreads();
    }

    // ---- epilogue: issue wE(31); L4(31) (wD from Y(31)); bar; L5(31) ----
#pragma unroll
    for (int ks = 0; ks < 2; ks++)
        wE[ks] = *(const bf16x8*)(Wf + (size_t)31 * 81920 + 73728 + ((size_t)(w * 2 + ks) * 64 + lane) * 8);
    do_l4(NE - 1);
    __syncthreads();
    do_l5(NE - 1);

    // ---- store: lane owns rows m*16+c, cols w*16 + q*4 .. +3 ----
#pragma unroll
    for (int m = 0; m < 4; m++)
        *(float4*)(out + (size_t)(b0 + m * 16 + c) * NOUT + w * 16 + q * 4) =
            (float4){oacc[m][0], oacc[m][1], oacc[m][2], oacc[m][3]};
}

extern "C" void kernel_launch(void* const* d_in, const int* in_sizes, int n_in,
                              void* d_out, int out_size, void* d_ws, size_t ws_size,
                              hipStream_t stream)
{
    (void)in_sizes; (void)n_in; (void)out_size; (void)ws_size;
    const float* x  = (const float*)d_in[0];
    const float* Wg = (const float*)d_in[1];
    const float* bg = (const float*)d_in[2];
    const float* W1 = (const float*)d_in[3];
    const float* b1 = (const float*)d_in[4];
    const float* W2 = (const float*)d_in[5];
    const float* b2 = (const float*)d_in[6];
    const float* W3 = (const float*)d_in[7];
    const float* b3 = (const float*)d_in[8];
    const float* W4 = (const float*)d_in[9];
    const float* b4 = (const float*)d_in[10];
    const float* W5 = (const float*)d_in[11];
    const float* b5 = (const float*)d_in[12];

    char* ws = (char*)d_ws;
    bf16_t* Wf  = (bf16_t*)(ws + OFF_WF);
    bf16_t* Wgf = (bf16_t*)(ws + OFF_WGF);
    float*  outp = (float*)d_out;

    build_frags<<<dim3(1284), dim3(256), 0, stream>>>(W1, W2, W3, W4, W5, Wg, Wf, Wgf);
    moe_main<<<dim3(BB / 64), dim3(512), 0, stream>>>(x, Wf, Wgf, bg,
                                                      b1, b2, b3, b4, b5, outp);
}